// Round 1
// baseline (4560.359 us; speedup 1.0000x reference)
//
#include <hip/hip_runtime.h>
#include <cmath>

#define BN   131072
#define Dd   128
#define Hh   64
#define Qq   32
#define HOR  28
#define TPB  256

__device__ __forceinline__ float sigm(float v) {
    return 1.0f / (1.0f + expf(-v));
}
__device__ __forceinline__ float tanh_fast(float v) {
    // tanh(v) = 1 - 2/(exp(2v)+1); correct at +-inf saturation
    float e = expf(2.0f * v);
    return 1.0f - 2.0f / (e + 1.0f);
}

__global__ __launch_bounds__(TPB) void predictor_kernel(
    const float* __restrict__ features,
    const float* __restrict__ last_value,
    const float* __restrict__ W_ih,
    const float* __restrict__ W_hh,
    const float* __restrict__ b_ih,
    const float* __restrict__ b_hh,
    const float* __restrict__ Wp,
    const float* __restrict__ bp,
    const float* __restrict__ Wo1,
    const float* __restrict__ bo1,
    const float* __restrict__ Wo2,
    const float* __restrict__ bo2,
    const float* __restrict__ Wg1,
    const float* __restrict__ bg1,
    const float* __restrict__ Wg2,
    const float* __restrict__ bg2,
    const float* __restrict__ log_decay,
    float* __restrict__ out)
{
    __shared__ float s_whh[192 * 64];   // 48 KB
    __shared__ float s_wo1[Qq * 64];    // 8 KB
    __shared__ float s_wih[192];
    __shared__ float s_bih[192];
    __shared__ float s_bhh[192];
    __shared__ float s_bo1[Qq];
    __shared__ float s_wo2[Qq];
    __shared__ float s_hn[TPB * 65];    // 66.5 KB, stride 65 -> 2-way bank alias (free)

    const int tid = threadIdx.x;

    for (int i = tid; i < 192 * 64; i += TPB) s_whh[i] = W_hh[i];
    for (int i = tid; i < Qq * 64;  i += TPB) s_wo1[i] = Wo1[i];
    if (tid < 192) { s_wih[tid] = W_ih[tid]; s_bih[tid] = b_ih[tid]; s_bhh[tid] = b_hh[tid]; }
    if (tid < Qq)  { s_bo1[tid] = bo1[tid]; s_wo2[tid] = Wo2[tid]; }
    __syncthreads();

    const int row = blockIdx.x * TPB + tid;
    const float* frow = features + (size_t)row * Dd;

    // ---- load feature row into registers (float4) ----
    float fr[Dd];
    #pragma unroll
    for (int k = 0; k < Dd / 4; ++k) {
        float4 v = ((const float4*)frow)[k];
        fr[4*k+0] = v.x; fr[4*k+1] = v.y; fr[4*k+2] = v.z; fr[4*k+3] = v.w;
    }

    // ---- gate path: sigmoid(relu(f@Wg1^T + bg1)@Wg2^T + bg2) -> stash into out ----
    float gacc[HOR];
    #pragma unroll
    for (int t = 0; t < HOR; ++t) gacc[t] = bg2[t];
    for (int q = 0; q < Qq; ++q) {
        const float4* wg = (const float4*)(Wg1 + q * Dd);   // uniform -> scalar loads
        float a0 = 0.f, a1 = 0.f, a2 = 0.f, a3 = 0.f;
        #pragma unroll
        for (int kk = 0; kk < Dd / 4; ++kk) {
            float4 w = wg[kk];
            a0 = fmaf(fr[4*kk+0], w.x, a0);
            a1 = fmaf(fr[4*kk+1], w.y, a1);
            a2 = fmaf(fr[4*kk+2], w.z, a2);
            a3 = fmaf(fr[4*kk+3], w.w, a3);
        }
        float a = fmaxf((a0 + a1) + (a2 + a3) + bg1[q], 0.f);
        #pragma unroll
        for (int t = 0; t < HOR; ++t) gacc[t] = fmaf(a, Wg2[t * Qq + q], gacc[t]);
    }
    #pragma unroll
    for (int t = 0; t < HOR; ++t) {
        out[(size_t)row * HOR + t] = sigm(gacc[t]);   // temp stash of gate
    }

    // ---- h0 = f @ Wp^T + bp  -> s_hn ----
    for (int u = 0; u < Hh; ++u) {
        const float4* wp = (const float4*)(Wp + u * Dd);    // uniform -> scalar loads
        float a0 = 0.f, a1 = 0.f, a2 = 0.f, a3 = 0.f;
        #pragma unroll
        for (int kk = 0; kk < Dd / 4; ++kk) {
            float4 w = wp[kk];
            a0 = fmaf(fr[4*kk+0], w.x, a0);
            a1 = fmaf(fr[4*kk+1], w.y, a1);
            a2 = fmaf(fr[4*kk+2], w.z, a2);
            a3 = fmaf(fr[4*kk+3], w.w, a3);
        }
        s_hn[tid * 65 + u] = (a0 + a1) + (a2 + a3) + bp[u];
    }

    // ---- recurrence ----
    const float lv  = last_value[row];
    float x = lv;
    const float ed = expf(log_decay[0]);
    const float bo2v = bo2[0];

    float h[Hh];
    #pragma unroll
    for (int i = 0; i < Hh; ++i) h[i] = s_hn[tid * 65 + i];

    for (int t = 0; t < HOR; ++t) {
        // GRU cell: 3 x (64-dot) per output unit
        for (int u = 0; u < Hh; ++u) {
            float gr = fmaf(x, s_wih[u],        s_bih[u])        + s_bhh[u];
            float gz = fmaf(x, s_wih[64 + u],   s_bih[64 + u])   + s_bhh[64 + u];
            float gn = fmaf(x, s_wih[128 + u],  s_bih[128 + u]);
            float ghn = s_bhh[128 + u];

            const float4* wr = (const float4*)(s_whh + u * 64);
            const float4* wz = (const float4*)(s_whh + (64 + u) * 64);
            const float4* wn = (const float4*)(s_whh + (128 + u) * 64);
            float r0=0.f,r1=0.f,r2=0.f,r3=0.f;
            float z0=0.f,z1=0.f,z2=0.f,z3=0.f;
            float n0=0.f,n1=0.f,n2=0.f,n3=0.f;
            #pragma unroll
            for (int kk = 0; kk < 16; ++kk) {
                float4 a = wr[kk];
                float4 b = wz[kk];
                float4 c = wn[kk];
                float h0v = h[4*kk+0], h1v = h[4*kk+1], h2v = h[4*kk+2], h3v = h[4*kk+3];
                r0 = fmaf(h0v, a.x, r0); r1 = fmaf(h1v, a.y, r1);
                r2 = fmaf(h2v, a.z, r2); r3 = fmaf(h3v, a.w, r3);
                z0 = fmaf(h0v, b.x, z0); z1 = fmaf(h1v, b.y, z1);
                z2 = fmaf(h2v, b.z, z2); z3 = fmaf(h3v, b.w, z3);
                n0 = fmaf(h0v, c.x, n0); n1 = fmaf(h1v, c.y, n1);
                n2 = fmaf(h2v, c.z, n2); n3 = fmaf(h3v, c.w, n3);
            }
            gr  += (r0 + r1) + (r2 + r3);
            gz  += (z0 + z1) + (z2 + z3);
            ghn += (n0 + n1) + (n2 + n3);

            float rg = sigm(gr);
            float zg = sigm(gz);
            float nc = tanh_fast(gn + rg * ghn);
            float hold = s_hn[tid * 65 + u];          // old h[u] (not yet overwritten)
            s_hn[tid * 65 + u] = (1.f - zg) * nc + zg * hold;
        }

        // reload new h into registers
        #pragma unroll
        for (int i = 0; i < Hh; ++i) h[i] = s_hn[tid * 65 + i];

        // pred = relu(h@Wo1^T + bo1) @ Wo2^T + bo2
        float pred = bo2v;
        for (int q = 0; q < Qq; ++q) {
            const float4* wo = (const float4*)(s_wo1 + q * 64);
            float a0=0.f,a1=0.f,a2=0.f,a3=0.f;
            #pragma unroll
            for (int kk = 0; kk < 16; ++kk) {
                float4 w = wo[kk];
                a0 = fmaf(h[4*kk+0], w.x, a0);
                a1 = fmaf(h[4*kk+1], w.y, a1);
                a2 = fmaf(h[4*kk+2], w.z, a2);
                a3 = fmaf(h[4*kk+3], w.w, a3);
            }
            float o = (a0 + a1) + (a2 + a3) + s_bo1[q];
            pred = fmaf(fmaxf(o, 0.f), s_wo2[q], pred);
        }

        // blend with decay path using stashed gate, overwrite out
        float g  = out[(size_t)row * HOR + t];
        float dc = expf(-ed * (float)(t + 1));
        out[(size_t)row * HOR + t] = g * pred + (1.f - g) * lv * dc;
        x = pred;
    }
}

extern "C" void kernel_launch(void* const* d_in, const int* in_sizes, int n_in,
                              void* d_out, int out_size, void* d_ws, size_t ws_size,
                              hipStream_t stream) {
    const float* features   = (const float*)d_in[0];
    const float* last_value = (const float*)d_in[1];
    const float* W_ih       = (const float*)d_in[2];
    const float* W_hh       = (const float*)d_in[3];
    const float* b_ih       = (const float*)d_in[4];
    const float* b_hh       = (const float*)d_in[5];
    const float* Wp         = (const float*)d_in[6];
    const float* bp         = (const float*)d_in[7];
    const float* Wo1        = (const float*)d_in[8];
    const float* bo1        = (const float*)d_in[9];
    const float* Wo2        = (const float*)d_in[10];
    const float* bo2        = (const float*)d_in[11];
    const float* Wg1        = (const float*)d_in[12];
    const float* bg1        = (const float*)d_in[13];
    const float* Wg2        = (const float*)d_in[14];
    const float* bg2        = (const float*)d_in[15];
    const float* log_decay  = (const float*)d_in[16];
    float* out = (float*)d_out;

    dim3 grid(BN / TPB), block(TPB);
    predictor_kernel<<<grid, block, 0, stream>>>(
        features, last_value, W_ih, W_hh, b_ih, b_hh, Wp, bp,
        Wo1, bo1, Wo2, bo2, Wg1, bg1, Wg2, bg2, log_decay, out);
}

// Round 2
// 354.207 us; speedup vs baseline: 12.8748x; 12.8748x over previous
//
#include <hip/hip_runtime.h>

#define TPB 256
#define HOR 28
#define BN  131072

typedef __attribute__((ext_vector_type(8))) short short8;
typedef __attribute__((ext_vector_type(4))) float f32x4;
typedef __attribute__((ext_vector_type(4))) unsigned uint4v;

union frag_u { unsigned u[4]; short8 s; };

#define MEMFENCE asm volatile("" ::: "memory")
#define LOG2E 1.44269504f

__device__ __forceinline__ unsigned bf_rne(unsigned fbits) {
    return (fbits + 0x7fffu + ((fbits >> 16) & 1u)) >> 16;
}
__device__ __forceinline__ short f2bf(float v) {
    union { float f; unsigned u; } c; c.f = v;
    return (short)bf_rne(c.u);
}
// pack: low16 = bf16(v) RNE ("hi" part), high16 = bf16 residual (truncated)
__device__ __forceinline__ unsigned pack_hilo(float v) {
    union { float f; unsigned u; } c; c.f = v;
    unsigned hi = bf_rne(c.u);
    union { unsigned u; float f; } hf; hf.u = hi << 16;
    union { float f; unsigned u; } d; d.f = v - hf.f;
    return (hi & 0xffffu) | (d.u & 0xffff0000u);
}
__device__ __forceinline__ float sigm2(float v) {
    float e = __builtin_amdgcn_exp2f(-LOG2E * v);
    return __builtin_amdgcn_rcpf(1.0f + e);
}
__device__ __forceinline__ float tanh2(float v) {
    float e = __builtin_amdgcn_exp2f(2.0f * LOG2E * v);
    return 1.0f - 2.0f * __builtin_amdgcn_rcpf(e + 1.0f);
}
// read 8 packed (hi|lo) u32 -> hi-frag and lo-frag (8 bf16 each, k-ascending pairs)
__device__ __forceinline__ void build_frags(const unsigned* p, frag_u& hi, frag_u& lo) {
    uint4v q0 = *(const uint4v*)p;
    uint4v q1 = *(const uint4v*)(p + 4);
    hi.u[0] = (q0[0] & 0xffffu) | (q0[1] << 16);
    hi.u[1] = (q0[2] & 0xffffu) | (q0[3] << 16);
    hi.u[2] = (q1[0] & 0xffffu) | (q1[1] << 16);
    hi.u[3] = (q1[2] & 0xffffu) | (q1[3] << 16);
    lo.u[0] = (q0[0] >> 16) | (q0[1] & 0xffff0000u);
    lo.u[1] = (q0[2] >> 16) | (q0[3] & 0xffff0000u);
    lo.u[2] = (q1[0] >> 16) | (q1[1] & 0xffff0000u);
    lo.u[3] = (q1[2] >> 16) | (q1[3] & 0xffff0000u);
}

#define MFMA(a, b, c) __builtin_amdgcn_mfma_f32_16x16x32_bf16((a), (b), (c), 0, 0, 0)

__global__ __launch_bounds__(TPB, 2) void predictor_kernel(
    const float* __restrict__ features,
    const float* __restrict__ last_value,
    const float* __restrict__ W_ih,
    const float* __restrict__ W_hh,
    const float* __restrict__ b_ih,
    const float* __restrict__ b_hh,
    const float* __restrict__ Wp,
    const float* __restrict__ bp,
    const float* __restrict__ Wo1,
    const float* __restrict__ bo1,
    const float* __restrict__ Wo2,
    const float* __restrict__ bo2,
    const float* __restrict__ Wg1,
    const float* __restrict__ bg1,
    const float* __restrict__ Wg2,
    const float* __restrict__ bg2,
    const float* __restrict__ log_decay,
    float* __restrict__ out)
{
    // union region: phase1 {Wp[64][136], Wg1[32][136]} | main {W_hh[192][72], Wo1[32][72]}
    __shared__ __align__(16) short s_wA[16128];
    __shared__ __align__(16) short s_wg2[32 * 48];
    __shared__ __align__(16) unsigned s_h[4][16 * 68];   // per-wave h bounce, packed hi|lo

    const int tid = threadIdx.x;
    const int wv  = tid >> 6;
    const int ln  = tid & 63;
    const int a   = ln & 15;    // A-row / C-col / B-col lane coordinate
    const int g   = ln >> 4;    // k-group lane coordinate
    const int wrow0 = blockIdx.x * 64 + wv * 16;

    short* s_wp  = s_wA;           // [64][136]
    short* s_wg1 = s_wA + 8704;    // [32][136]

    for (int i = tid; i < 64 * 128; i += TPB) s_wp [(i >> 7) * 136 + (i & 127)] = f2bf(Wp[i]);
    for (int i = tid; i < 32 * 128; i += TPB) s_wg1[(i >> 7) * 136 + (i & 127)] = f2bf(Wg1[i]);
    for (int i = tid; i < 32 * 48; i += TPB) {
        int t = i / 48, q = i - t * 48;
        s_wg2[i] = (t < HOR && q < 32) ? f2bf(Wg2[t * 32 + q]) : (short)0;
    }

    // ---- per-lane constants ----
    float wihR[4], wihZ[4], wihN[4], brc[4], bzc[4], binc[4], bhnc[4], bpc[4];
    #pragma unroll
    for (int c = 0; c < 4; ++c) {
        int u = a + 16 * c;
        wihR[c] = W_ih[u]; wihZ[c] = W_ih[64 + u]; wihN[c] = W_ih[128 + u];
        brc[c]  = b_ih[u] + b_hh[u];
        bzc[c]  = b_ih[64 + u] + b_hh[64 + u];
        binc[c] = b_ih[128 + u];
        bhnc[c] = b_hh[128 + u];
        bpc[c]  = bp[u];
    }
    const float wo2c0 = Wo2[a],  wo2c1 = Wo2[a + 16];
    const float bo1c0 = bo1[a],  bo1c1 = bo1[a + 16];
    const float bg1c0 = bg1[a],  bg1c1 = bg1[a + 16];
    const float bg2c0 = bg2[a],  bg2c1 = (a < HOR - 16) ? bg2[a + 16] : 0.0f;
    const float bo2v  = bo2[0];
    const float ed    = __builtin_amdgcn_exp2f(LOG2E * log_decay[0]);
    const float edc   = LOG2E * ed;

    f32x4 lv4, x4;
    #pragma unroll
    for (int r = 0; r < 4; ++r) lv4[r] = last_value[wrow0 + g * 4 + r];
    x4 = lv4;

    // ---- feature A-fragments (hi/lo) ----
    frag_u fhi[4], flo[4];
    #pragma unroll
    for (int kt = 0; kt < 4; ++kt) {
        const float* fp = features + (size_t)(wrow0 + a) * 128 + kt * 32 + g * 8;
        f32x4 v0 = *(const f32x4*)fp;
        f32x4 v1 = *(const f32x4*)(fp + 4);
        float fv[8] = {v0[0], v0[1], v0[2], v0[3], v1[0], v1[1], v1[2], v1[3]};
        #pragma unroll
        for (int p = 0; p < 4; ++p) {
            unsigned w0 = pack_hilo(fv[2 * p]);
            unsigned w1 = pack_hilo(fv[2 * p + 1]);
            fhi[kt].u[p] = (w0 & 0xffffu) | (w1 << 16);
            flo[kt].u[p] = (w0 >> 16) | (w1 & 0xffff0000u);
        }
    }

    __syncthreads();

    // ---- h0 = feat @ Wp^T + bp ----
    f32x4 h0acc[4];
    #pragma unroll
    for (int nt = 0; nt < 4; ++nt) h0acc[nt] = (f32x4){bpc[nt], bpc[nt], bpc[nt], bpc[nt]};
    #pragma unroll
    for (int nt = 0; nt < 4; ++nt) {
        #pragma unroll
        for (int kt = 0; kt < 4; ++kt) {
            short8 b = *(const short8*)&s_wp[(nt * 16 + a) * 136 + kt * 32 + g * 8];
            h0acc[nt] = MFMA(fhi[kt].s, b, h0acc[nt]);
            h0acc[nt] = MFMA(flo[kt].s, b, h0acc[nt]);
        }
    }

    // ---- gate path: relu(feat@Wg1^T + bg1) @ Wg2^T + bg2, sigmoid ----
    f32x4 g1acc[2] = {{bg1c0, bg1c0, bg1c0, bg1c0}, {bg1c1, bg1c1, bg1c1, bg1c1}};
    #pragma unroll
    for (int mt = 0; mt < 2; ++mt) {
        #pragma unroll
        for (int kt = 0; kt < 4; ++kt) {
            short8 b = *(const short8*)&s_wg1[(mt * 16 + a) * 136 + kt * 32 + g * 8];
            g1acc[mt] = MFMA(fhi[kt].s, b, g1acc[mt]);
            g1acc[mt] = MFMA(flo[kt].s, b, g1acc[mt]);
        }
    }
    #pragma unroll
    for (int mt = 0; mt < 2; ++mt)
        #pragma unroll
        for (int r = 0; r < 4; ++r)
            s_h[wv][(g * 4 + r) * 68 + a + 16 * mt] = pack_hilo(fmaxf(g1acc[mt][r], 0.f));
    MEMFENCE;
    frag_u a2hi, a2lo;
    build_frags(&s_h[wv][a * 68 + g * 8], a2hi, a2lo);
    f32x4 g2acc[2] = {{bg2c0, bg2c0, bg2c0, bg2c0}, {bg2c1, bg2c1, bg2c1, bg2c1}};
    #pragma unroll
    for (int mt = 0; mt < 2; ++mt) {
        short8 b = *(const short8*)&s_wg2[(mt * 16 + a) * 48 + g * 8];
        g2acc[mt] = MFMA(a2hi.s, b, g2acc[mt]);
        g2acc[mt] = MFMA(a2lo.s, b, g2acc[mt]);
    }
    f32x4 gv0, gv1;
    #pragma unroll
    for (int r = 0; r < 4; ++r) { gv0[r] = sigm2(g2acc[0][r]); gv1[r] = sigm2(g2acc[1][r]); }

    // ---- restage: W_hh, Wo1 into union region ----
    __syncthreads();
    short* s_whh = s_wA;            // [192][72]
    short* s_wo1 = s_wA + 13824;    // [32][72]
    for (int i = tid; i < 192 * 64; i += TPB) s_whh[(i >> 6) * 72 + (i & 63)] = f2bf(W_hh[i]);
    for (int i = tid; i < 32 * 64;  i += TPB) s_wo1[(i >> 6) * 72 + (i & 63)] = f2bf(Wo1[i]);
    __syncthreads();

    // ---- h state: f32 regs + packed LDS + frags ----
    f32x4 h4[4];
    #pragma unroll
    for (int c = 0; c < 4; ++c) h4[c] = h0acc[c];
    #pragma unroll
    for (int c = 0; c < 4; ++c)
        #pragma unroll
        for (int r = 0; r < 4; ++r)
            s_h[wv][(g * 4 + r) * 68 + a + 16 * c] = pack_hilo(h4[c][r]);
    MEMFENCE;
    frag_u Fhi[2], Flo[2];
    #pragma unroll
    for (int kt = 0; kt < 2; ++kt)
        build_frags(&s_h[wv][a * 68 + kt * 32 + g * 8], Fhi[kt], Flo[kt]);

    // ---- 28-step recurrence (no barriers) ----
    #pragma unroll 1
    for (int t = 0; t < HOR; ++t) {
        f32x4 acc[12];
        #pragma unroll
        for (int nt = 0; nt < 12; ++nt) acc[nt] = (f32x4){0.f, 0.f, 0.f, 0.f};
        #pragma unroll
        for (int nt = 0; nt < 12; ++nt) {
            #pragma unroll
            for (int kt = 0; kt < 2; ++kt) {
                short8 b = *(const short8*)&s_whh[(nt * 16 + a) * 72 + kt * 32 + g * 8];
                acc[nt] = MFMA(Fhi[kt].s, b, acc[nt]);
                acc[nt] = MFMA(Flo[kt].s, b, acc[nt]);
            }
        }
        // elementwise GRU cell (lane-local)
        #pragma unroll
        for (int c = 0; c < 4; ++c) {
            #pragma unroll
            for (int r = 0; r < 4; ++r) {
                float xv  = x4[r];
                float rh  = fmaf(xv, wihR[c], brc[c]) + acc[c][r];
                float zh  = fmaf(xv, wihZ[c], bzc[c]) + acc[4 + c][r];
                float gin = fmaf(xv, wihN[c], binc[c]);
                float ghn = acc[8 + c][r] + bhnc[c];
                float rg  = sigm2(rh);
                float zg  = sigm2(zh);
                float nc  = tanh2(fmaf(rg, ghn, gin));
                float hn  = nc + zg * (h4[c][r] - nc);
                h4[c][r]  = hn;
                s_h[wv][(g * 4 + r) * 68 + a + 16 * c] = pack_hilo(hn);
            }
        }
        MEMFENCE;
        #pragma unroll
        for (int kt = 0; kt < 2; ++kt)
            build_frags(&s_h[wv][a * 68 + kt * 32 + g * 8], Fhi[kt], Flo[kt]);

        // head: pred = relu(h@Wo1^T + bo1) @ Wo2^T + bo2
        f32x4 pa0 = {bo1c0, bo1c0, bo1c0, bo1c0};
        f32x4 pa1 = {bo1c1, bo1c1, bo1c1, bo1c1};
        #pragma unroll
        for (int kt = 0; kt < 2; ++kt) {
            short8 b0 = *(const short8*)&s_wo1[(a) * 72 + kt * 32 + g * 8];
            short8 b1 = *(const short8*)&s_wo1[(16 + a) * 72 + kt * 32 + g * 8];
            pa0 = MFMA(Fhi[kt].s, b0, pa0);
            pa0 = MFMA(Flo[kt].s, b0, pa0);
            pa1 = MFMA(Fhi[kt].s, b1, pa1);
            pa1 = MFMA(Flo[kt].s, b1, pa1);
        }
        f32x4 part;
        #pragma unroll
        for (int r = 0; r < 4; ++r)
            part[r] = fmaxf(pa0[r], 0.f) * wo2c0 + fmaxf(pa1[r], 0.f) * wo2c1;
        #pragma unroll
        for (int m = 1; m <= 8; m <<= 1) {
            #pragma unroll
            for (int r = 0; r < 4; ++r)
                part[r] += __shfl_xor(part[r], m);
        }
        #pragma unroll
        for (int r = 0; r < 4; ++r) x4[r] = part[r] + bo2v;

        // blend + store (4 lanes per wave own column t)
        float dc = __builtin_amdgcn_exp2f(-edc * (float)(t + 1));
        if (a == (t & 15)) {
            f32x4 gc = (t & 16) ? gv1 : gv0;
            #pragma unroll
            for (int r = 0; r < 4; ++r) {
                float o = gc[r] * x4[r] + (1.f - gc[r]) * lv4[r] * dc;
                out[(size_t)(wrow0 + g * 4 + r) * HOR + t] = o;
            }
        }
    }
}

extern "C" void kernel_launch(void* const* d_in, const int* in_sizes, int n_in,
                              void* d_out, int out_size, void* d_ws, size_t ws_size,
                              hipStream_t stream) {
    const float* features   = (const float*)d_in[0];
    const float* last_value = (const float*)d_in[1];
    const float* W_ih       = (const float*)d_in[2];
    const float* W_hh       = (const float*)d_in[3];
    const float* b_ih       = (const float*)d_in[4];
    const float* b_hh       = (const float*)d_in[5];
    const float* Wp         = (const float*)d_in[6];
    const float* bp         = (const float*)d_in[7];
    const float* Wo1        = (const float*)d_in[8];
    const float* bo1        = (const float*)d_in[9];
    const float* Wo2        = (const float*)d_in[10];
    const float* bo2        = (const float*)d_in[11];
    const float* Wg1        = (const float*)d_in[12];
    const float* bg1        = (const float*)d_in[13];
    const float* Wg2        = (const float*)d_in[14];
    const float* bg2        = (const float*)d_in[15];
    const float* log_decay  = (const float*)d_in[16];
    float* out = (float*)d_out;

    dim3 grid(BN / 64), block(TPB);
    predictor_kernel<<<grid, block, 0, stream>>>(
        features, last_value, W_ih, W_hh, b_ih, b_hh, Wp, bp,
        Wo1, bo1, Wo2, bo2, Wg1, bg1, Wg2, bg2, log_decay, out);
}

// Round 5
// 247.274 us; speedup vs baseline: 18.4425x; 1.4324x over previous
//
#include <hip/hip_runtime.h>

#define TPB 256
#define HOR 28
#define LOG2E 1.44269504088896340736f

typedef _Float16 f16;
typedef __attribute__((ext_vector_type(2))) _Float16 f16x2;
typedef __attribute__((ext_vector_type(4))) _Float16 f16x4;
typedef __attribute__((ext_vector_type(8))) _Float16 f16x8;
typedef __attribute__((ext_vector_type(4))) float f32x4;

union V8 { f16x8 v8; f16x4 v4[2]; f16x2 h2[4]; };

#define MFMA16(A,B,C) __builtin_amdgcn_mfma_f32_16x16x32_f16((A),(B),(C),0,0,0)

__device__ __forceinline__ f16x2 pk2(float a, float b) {
    return __builtin_bit_cast(f16x2, __builtin_amdgcn_cvt_pkrtz(a, b));
}

__global__ __launch_bounds__(TPB, 2) void predictor_kernel(
    const float* __restrict__ features,
    const float* __restrict__ last_value,
    const float* __restrict__ W_ih,
    const float* __restrict__ W_hh,
    const float* __restrict__ b_ih,
    const float* __restrict__ b_hh,
    const float* __restrict__ Wp,
    const float* __restrict__ bp,
    const float* __restrict__ Wo1,
    const float* __restrict__ bo1,
    const float* __restrict__ Wo2,
    const float* __restrict__ bo2,
    const float* __restrict__ Wg1,
    const float* __restrict__ bg1,
    const float* __restrict__ Wg2,
    const float* __restrict__ bg2,
    const float* __restrict__ log_decay,
    float* __restrict__ out)
{
    __shared__ f16 s_whh[192 * 72];   // scaled, natural col order
    __shared__ f16 s_wo1[32 * 72];
    __shared__ f16 s_wp [64 * 136];
    __shared__ f16 s_wg1[32 * 136];
    __shared__ f16 s_wg2[32 * 40];    // sigma''-permuted cols

    const int tid = threadIdx.x;
    const int wv = tid >> 6, ln = tid & 63;
    const int a = ln & 15, g = ln >> 4;
    const int row0 = blockIdx.x * 64 + wv * 16;

    const f32x4 ZF = {0.f, 0.f, 0.f, 0.f};

    // ---- stage weights (f16, exp2-scales folded in) ----
    for (int i = tid; i < 192 * 64; i += TPB) {
        int r = i >> 6, c = i & 63;
        float s = (r < 128) ? -LOG2E : 2.0f * LOG2E;
        s_whh[r * 72 + c] = (f16)(W_hh[i] * s);
    }
    for (int i = tid; i < 32 * 64; i += TPB) s_wo1[(i >> 6) * 72 + (i & 63)] = (f16)Wo1[i];
    for (int i = tid; i < 64 * 128; i += TPB) s_wp [(i >> 7) * 136 + (i & 127)] = (f16)Wp[i];
    for (int i = tid; i < 32 * 128; i += TPB) s_wg1[(i >> 7) * 136 + (i & 127)] = (f16)Wg1[i];
    for (int i = tid; i < 32 * 32; i += TPB) {
        int t = i >> 5, s = i & 31;
        int q = ((s >> 2) & 1) * 16 + ((s >> 3) & 3) * 4 + (s & 3);   // sigma''
        s_wg2[t * 40 + s] = (f16)((t < HOR) ? Wg2[t * 32 + q] : 0.0f);
    }

    // ---- per-lane packed constants (unit u = 16c + 4g + r) ----
    f16x2 wR[4][2], wZ[4][2], wN[4][2], bR[4][2], bZ[4][2], bN[4][2], bH[4][2];
    #pragma unroll
    for (int c = 0; c < 4; ++c) {
        #pragma unroll
        for (int p = 0; p < 2; ++p) {
            int u0 = c * 16 + g * 4 + 2 * p, u1 = u0 + 1;
            wR[c][p] = pk2(W_ih[u0] * -LOG2E, W_ih[u1] * -LOG2E);
            wZ[c][p] = pk2(W_ih[64 + u0] * -LOG2E, W_ih[64 + u1] * -LOG2E);
            wN[c][p] = pk2(W_ih[128 + u0] * 2.0f * LOG2E, W_ih[128 + u1] * 2.0f * LOG2E);
            bR[c][p] = pk2((b_ih[u0] + b_hh[u0]) * -LOG2E, (b_ih[u1] + b_hh[u1]) * -LOG2E);
            bZ[c][p] = pk2((b_ih[64 + u0] + b_hh[64 + u0]) * -LOG2E,
                           (b_ih[64 + u1] + b_hh[64 + u1]) * -LOG2E);
            bN[c][p] = pk2(b_ih[128 + u0] * 2.0f * LOG2E, b_ih[128 + u1] * 2.0f * LOG2E);
            bH[c][p] = pk2(b_hh[128 + u0] * 2.0f * LOG2E, b_hh[128 + u1] * 2.0f * LOG2E);
        }
    }
    f16x2 bo1q[2][2], wo2q[2][2];
    #pragma unroll
    for (int mt = 0; mt < 2; ++mt)
        #pragma unroll
        for (int p = 0; p < 2; ++p) {
            int q0 = mt * 16 + g * 4 + 2 * p;
            bo1q[mt][p] = pk2(bo1[q0], bo1[q0 + 1]);
            wo2q[mt][p] = pk2(Wo2[q0], Wo2[q0 + 1]);
        }
    const float bo2v = bo2[0];
    const float edc  = LOG2E * __builtin_amdgcn_exp2f(LOG2E * log_decay[0]);
    const float lv   = last_value[row0 + a];

    // ---- feature fragments (f16, natural k order) ----
    V8 FF[4];
    #pragma unroll
    for (int kt = 0; kt < 4; ++kt) {
        const float* fp = features + (size_t)(row0 + a) * 128 + kt * 32 + g * 8;
        f32x4 v0 = *(const f32x4*)fp;
        f32x4 v1 = *(const f32x4*)(fp + 4);
        FF[kt].h2[0] = pk2(v0[0], v0[1]); FF[kt].h2[1] = pk2(v0[2], v0[3]);
        FF[kt].h2[2] = pk2(v1[0], v1[1]); FF[kt].h2[3] = pk2(v1[2], v1[3]);
    }

    __syncthreads();

    // ---- h0 = feat @ Wp^T + bp : lane(a,g) reg r -> batch a, unit 16nt+4g+r ----
    f32x4 h4[4];
    {
        f16x2 bpq[4][2];
        #pragma unroll
        for (int c = 0; c < 4; ++c)
            #pragma unroll
            for (int p = 0; p < 2; ++p) {
                int u0 = c * 16 + g * 4 + 2 * p;
                bpq[c][p] = pk2(bp[u0], bp[u0 + 1]);
            }
        #pragma unroll
        for (int nt = 0; nt < 4; ++nt) {
            f32x4 acc = ZF;
            #pragma unroll
            for (int kt = 0; kt < 4; ++kt) {
                f16x8 w = *(const f16x8*)&s_wp[(nt * 16 + a) * 136 + kt * 32 + g * 8];
                acc = MFMA16(w, FF[kt].v8, acc);
            }
            #pragma unroll
            for (int r = 0; r < 4; ++r) acc[r] += (float)bpq[nt][r >> 1][r & 1];
            h4[nt] = acc;
        }
    }

    // ---- gate path ----
    float gA0, gA1, gA2, gA3, gB0, gB1, gB2, gB3;
    {
        f32x4 a1acc[2];
        #pragma unroll
        for (int mt = 0; mt < 2; ++mt) {
            f32x4 acc = ZF;
            #pragma unroll
            for (int kt = 0; kt < 4; ++kt) {
                f16x8 w = *(const f16x8*)&s_wg1[(mt * 16 + a) * 136 + kt * 32 + g * 8];
                acc = MFMA16(w, FF[kt].v8, acc);
            }
            #pragma unroll
            for (int r = 0; r < 4; ++r) {
                int q0 = mt * 16 + g * 4 + r;
                acc[r] = fmaxf(acc[r] + bg1[q0], 0.f);
            }
            a1acc[mt] = acc;
        }
        V8 A1;
        A1.h2[0] = pk2(a1acc[0][0], a1acc[0][1]);
        A1.h2[1] = pk2(a1acc[0][2], a1acc[0][3]);
        A1.h2[2] = pk2(a1acc[1][0], a1acc[1][1]);
        A1.h2[3] = pk2(a1acc[1][2], a1acc[1][3]);
        float gv[2][4];
        #pragma unroll
        for (int mt = 0; mt < 2; ++mt) {
            f32x4 acc = ZF;
            f16x8 w = *(const f16x8*)&s_wg2[(mt * 16 + a) * 40 + g * 8];
            acc = MFMA16(w, A1.v8, acc);
            #pragma unroll
            for (int r = 0; r < 4; ++r) {
                int t0 = mt * 16 + g * 4 + r;
                float lg = acc[r] + ((t0 < HOR) ? bg2[t0] : 0.f);
                gv[mt][r] = __builtin_amdgcn_rcpf(1.0f + __builtin_amdgcn_exp2f(-LOG2E * lg));
            }
        }
        gA0 = gv[0][0]; gA1 = gv[0][1]; gA2 = gv[0][2]; gA3 = gv[0][3];
        gB0 = gv[1][0]; gB1 = gv[1][1]; gB2 = gv[1][2]; gB3 = gv[1][3];
    }

    // ---- loop-invariant W_hh fragments into registers (sigma cols) ----
    V8 WgR[4][2], WgZ[4][2], WgN[4][2];
    #pragma unroll
    for (int c = 0; c < 4; ++c) {
        #pragma unroll
        for (int kt = 0; kt < 2; ++kt) {
            int rowR = (c * 16 + a) * 72 + kt * 32 + 4 * g;
            int rowZ = (64 + c * 16 + a) * 72 + kt * 32 + 4 * g;
            int rowN = (128 + c * 16 + a) * 72 + kt * 32 + 4 * g;
            WgR[c][kt].v4[0] = *(const f16x4*)&s_whh[rowR];
            WgR[c][kt].v4[1] = *(const f16x4*)&s_whh[rowR + 16];
            WgZ[c][kt].v4[0] = *(const f16x4*)&s_whh[rowZ];
            WgZ[c][kt].v4[1] = *(const f16x4*)&s_whh[rowZ + 16];
            WgN[c][kt].v4[0] = *(const f16x4*)&s_whh[rowN];
            WgN[c][kt].v4[1] = *(const f16x4*)&s_whh[rowN + 16];
        }
    }

    // ---- pack initial h fragments ----
    V8 F0, F1;
    F0.h2[0] = pk2(h4[0][0], h4[0][1]); F0.h2[1] = pk2(h4[0][2], h4[0][3]);
    F0.h2[2] = pk2(h4[1][0], h4[1][1]); F0.h2[3] = pk2(h4[1][2], h4[1][3]);
    F1.h2[0] = pk2(h4[2][0], h4[2][1]); F1.h2[1] = pk2(h4[2][2], h4[2][3]);
    F1.h2[2] = pk2(h4[3][0], h4[3][1]); F1.h2[3] = pk2(h4[3][2], h4[3][3]);

    float x = lv;

#define GATE_MMA(ACC, WARR, c) do { \
        ACC = MFMA16(WARR[c][0].v8, F0.v8, ZF); \
        ACC = MFMA16(WARR[c][1].v8, F1.v8, ACC); } while (0)

#define GRU_CELL(c, AR, AZ, AN) do { \
        _Pragma("unroll") \
        for (int p = 0; p < 2; ++p) { \
            f16x2 afR = x2 * wR[c][p] + bR[c][p]; \
            f16x2 afZ = x2 * wZ[c][p] + bZ[c][p]; \
            f16x2 afN = x2 * wN[c][p] + bN[c][p]; \
            _Pragma("unroll") \
            for (int q = 0; q < 2; ++q) { \
                int r = p * 2 + q; \
                float ar = AR[r] + (float)afR[q]; \
                float rg = __builtin_amdgcn_rcpf(1.0f + __builtin_amdgcn_exp2f(ar)); \
                float az = AZ[r] + (float)afZ[q]; \
                float pb = 1.0f + __builtin_amdgcn_exp2f(az); \
                float ghn = AN[r] + (float)bH[c][p][q]; \
                float E  = __builtin_amdgcn_exp2f(fmaf(rg, ghn, (float)afN[q])); \
                float pE = 1.0f + E; \
                float rD = __builtin_amdgcn_rcpf(pb * pE); \
                float zg = rD * pE; \
                float ivE = rD * pb; \
                float nc = fmaf(-2.0f, ivE, 1.0f); \
                float hv = h4[c][r]; \
                h4[c][r] = fmaf(zg, hv - nc, nc); \
            } \
        } } while (0)

    #pragma unroll 1
    for (int t = 0; t < HOR; ++t) {
        f16x2 x2 = pk2(x, x);
        f32x4 aR0, aZ0, aN0, aR1, aZ1, aN1;
        // half 0: unit classes c=0,1
        GATE_MMA(aR0, WgR, 0); GATE_MMA(aZ0, WgZ, 0); GATE_MMA(aN0, WgN, 0);
        GATE_MMA(aR1, WgR, 1); GATE_MMA(aZ1, WgZ, 1); GATE_MMA(aN1, WgN, 1);
        GRU_CELL(0, aR0, aZ0, aN0);
        GRU_CELL(1, aR1, aZ1, aN1);
        // half 1: c=2,3 (reuse acc registers)
        GATE_MMA(aR0, WgR, 2); GATE_MMA(aZ0, WgZ, 2); GATE_MMA(aN0, WgN, 2);
        GATE_MMA(aR1, WgR, 3); GATE_MMA(aZ1, WgZ, 3); GATE_MMA(aN1, WgN, 3);
        GRU_CELL(2, aR0, aZ0, aN0);
        GRU_CELL(3, aR1, aZ1, aN1);

        // pack new h fragments (in-lane, sigma makes this local)
        F0.h2[0] = pk2(h4[0][0], h4[0][1]); F0.h2[1] = pk2(h4[0][2], h4[0][3]);
        F0.h2[2] = pk2(h4[1][0], h4[1][1]); F0.h2[3] = pk2(h4[1][2], h4[1][3]);
        F1.h2[0] = pk2(h4[2][0], h4[2][1]); F1.h2[1] = pk2(h4[2][2], h4[2][3]);
        F1.h2[2] = pk2(h4[3][0], h4[3][1]); F1.h2[3] = pk2(h4[3][2], h4[3][3]);

        // head: o = relu(h@Wo1^T + bo1) @ Wo2^T + bo2  (Wo1 frags from LDS, sigma cols)
        V8 wo;
        f32x4 o0 = ZF, o1 = ZF;
        wo.v4[0] = *(const f16x4*)&s_wo1[a * 72 + 4 * g];
        wo.v4[1] = *(const f16x4*)&s_wo1[a * 72 + 16 + 4 * g];
        o0 = MFMA16(wo.v8, F0.v8, o0);
        wo.v4[0] = *(const f16x4*)&s_wo1[a * 72 + 32 + 4 * g];
        wo.v4[1] = *(const f16x4*)&s_wo1[a * 72 + 48 + 4 * g];
        o0 = MFMA16(wo.v8, F1.v8, o0);
        wo.v4[0] = *(const f16x4*)&s_wo1[(16 + a) * 72 + 4 * g];
        wo.v4[1] = *(const f16x4*)&s_wo1[(16 + a) * 72 + 16 + 4 * g];
        o1 = MFMA16(wo.v8, F0.v8, o1);
        wo.v4[0] = *(const f16x4*)&s_wo1[(16 + a) * 72 + 32 + 4 * g];
        wo.v4[1] = *(const f16x4*)&s_wo1[(16 + a) * 72 + 48 + 4 * g];
        o1 = MFMA16(wo.v8, F1.v8, o1);

        float part = 0.f;
        #pragma unroll
        for (int p = 0; p < 2; ++p)
            #pragma unroll
            for (int q = 0; q < 2; ++q) {
                int r = 2 * p + q;
                part += fmaxf(o0[r] + (float)bo1q[0][p][q], 0.f) * (float)wo2q[0][p][q];
                part += fmaxf(o1[r] + (float)bo1q[1][p][q], 0.f) * (float)wo2q[1][p][q];
            }
        part += __shfl_xor(part, 16);
        part += __shfl_xor(part, 32);
        float pred = part + bo2v;

        // blend + store: one g-subgroup owns column t
        if (g == ((t >> 2) & 3)) {
            float s01 = (t & 1) ? ((t & 16) ? gB1 : gA1) : ((t & 16) ? gB0 : gA0);
            float s23 = (t & 1) ? ((t & 16) ? gB3 : gA3) : ((t & 16) ? gB2 : gA2);
            float gvf = (t & 2) ? s23 : s01;
            float dc = __builtin_amdgcn_exp2f(-edc * (float)(t + 1));
            float lvdc = lv * dc;
            out[(size_t)(row0 + a) * HOR + t] = fmaf(gvf, pred - lvdc, lvdc);
        }
        x = pred;
    }
#undef GATE_MMA
#undef GRU_CELL
}

extern "C" void kernel_launch(void* const* d_in, const int* in_sizes, int n_in,
                              void* d_out, int out_size, void* d_ws, size_t ws_size,
                              hipStream_t stream) {
    const float* features   = (const float*)d_in[0];
    const float* last_value = (const float*)d_in[1];
    const float* W_ih       = (const float*)d_in[2];
    const float* W_hh       = (const float*)d_in[3];
    const float* b_ih       = (const float*)d_in[4];
    const float* b_hh       = (const float*)d_in[5];
    const float* Wp         = (const float*)d_in[6];
    const float* bp         = (const float*)d_in[7];
    const float* Wo1        = (const float*)d_in[8];
    const float* bo1        = (const float*)d_in[9];
    const float* Wo2        = (const float*)d_in[10];
    const float* bo2        = (const float*)d_in[11];
    const float* Wg1        = (const float*)d_in[12];
    const float* bg1        = (const float*)d_in[13];
    const float* Wg2        = (const float*)d_in[14];
    const float* bg2        = (const float*)d_in[15];
    const float* log_decay  = (const float*)d_in[16];
    float* out = (float*)d_out;

    dim3 grid(131072 / 64), block(TPB);
    predictor_kernel<<<grid, block, 0, stream>>>(
        features, last_value, W_ih, W_hh, b_ih, b_hh, Wp, bp,
        Wo1, bo1, Wo2, bo2, Wg1, bg1, Wg2, bg2, log_decay, out);
}